// Round 7
// baseline (74.672 us; speedup 1.0000x reference)
//
#include <hip/hip_runtime.h>
#include <hip/hip_bf16.h>

#define NNODES 20000
#define NE_RAW 200000
#define NE_TOT 220000
#define MAX1   128
#define MAX2   512
#define MAXE1  4096
#define MAXE2  256
#define FIN    1280
#define FH     1024
#define HC     256
#define NHEAD  4
#define C2     128
#define CAPE   512
#define KCK    64       // k per chunk
#define NKC    20       // 20 x 64 = 1280
#define NRS    4        // row-splits (R7: 2 -> 4 for occupancy)
#define HH_GEMM_BLOCKS 640   // 20 kc x 8 ct x 4 row-splits

__device__ __forceinline__ float lrelu(float x){ return x >= 0.f ? x : 0.2f * x; }

// K0: reset slot maps + counters
__global__ void k_init(int* cnt, int* slot1, int* slot2){
  int i = blockIdx.x * 256 + threadIdx.x;
  if (i < NNODES){ slot1[i] = -1; slot2[i] = -1; }
  if (i < 8) cnt[i] = 0;
}

// K1: S1 = in-neighbors of mutation_idx (incl. self-loop), E2 = edges into mi
__global__ void k_scan1(const int* __restrict__ ei, const int* __restrict__ mip,
                        int* cnt, int* slot1, int* S1, int* E2){
  int e = blockIdx.x * 256 + threadIdx.x;
  if (e >= NE_TOT) return;
  int mi = mip[0];
  int src, dst;
  if (e < NE_RAW){ src = ei[e]; dst = ei[NE_RAW + e]; }
  else { src = e - NE_RAW; dst = src; }
  if (dst != mi) return;
  int p = atomicAdd(&cnt[3], 1);
  if (p < MAXE2) E2[p] = src;
  if (atomicCAS(&slot1[src], -1, -9) == -1){
    int idx = atomicAdd(&cnt[0], 1);
    if (idx < MAX1){ S1[idx] = src; slot1[src] = idx; }
  }
}

// K2: S2 = in-neighbors of S1; E1 = edge occurrences into S1
__global__ void k_scan2(const int* __restrict__ ei, int* cnt,
                        const int* __restrict__ slot1, int* slot2,
                        int* S2, int* E1s, int* E1d){
  int e = blockIdx.x * 256 + threadIdx.x;
  if (e >= NE_TOT) return;
  int src, dst;
  if (e < NE_RAW){ src = ei[e]; dst = ei[NE_RAW + e]; }
  else { src = e - NE_RAW; dst = src; }
  if (slot1[dst] < 0) return;
  int p = atomicAdd(&cnt[2], 1);
  if (p < MAXE1){ E1s[p] = src; E1d[p] = dst; }
  if (atomicCAS(&slot2[src], -1, -9) == -1){
    int idx = atomicAdd(&cnt[1], 1);
    if (idx < MAX2){ S2[idx] = src; slot2[src] = idx; }
  }
}

// K3: LDS-tiled pruned GEMM. Block = (kc, ct, rs). W-tile [64k x 128c] staged once
// (32 KB), x-tile transposed [64k x 32r] per row-group (8 KB). rs=4 row-splits:
// 640 blocks -> ~2.5 blocks/CU (10 waves/CU) so LDS/global latency is hidden.
// Blocks HH_GEMM_BLOCKS.. : pmd stage-1 GEMV r1 = relu(msd@Wm1+bm1).
__global__ __launch_bounds__(256) void k_hh(
    const float* __restrict__ x, const float* __restrict__ W1,
    const float* __restrict__ msd, const float* __restrict__ Wm1,
    const float* __restrict__ bm1,
    const int* __restrict__ cnt, const int* __restrict__ S2,
    float* __restrict__ hpart, float* __restrict__ r1){
  int t = threadIdx.x;
  if (blockIdx.x >= HH_GEMM_BLOCKS){
    __shared__ float red[256];
    int b   = blockIdx.x - HH_GEMM_BLOCKS;   // 0..3 -> 32 cols each
    int col = b * 32 + (t & 31);
    int sl  = t >> 5;                        // 8 k-slices of 128
    float s = 0.f;
    for (int k = sl * 128; k < sl * 128 + 128; ++k)
      s += msd[k] * Wm1[k * C2 + col];
    red[t] = s;
    __syncthreads();
    if (t < 32){
      float v = 0.f;
      #pragma unroll
      for (int q = 0; q < 8; ++q) v += red[q * 32 + t];
      v += bm1[col];
      r1[col] = v > 0.f ? v : 0.f;
    }
    return;
  }
  __shared__ float Wl[KCK][128];   // 32 KB
  __shared__ float Xl[KCK][32];    // 8 KB, transposed: [k][row]
  int bid = blockIdx.x;
  int rs = bid & 3, ct = (bid >> 2) & 7, kc = bid >> 5;
  int k0 = kc * KCK, c0 = ct * 128;
  int n2 = cnt[1]; if (n2 > MAX2) n2 = MAX2;
  for (int idx = t; idx < 2048; idx += 256){
    int r = idx >> 5, c4 = idx & 31;
    *(float4*)&Wl[r][c4 * 4] = *(const float4*)(W1 + (long)(k0 + r) * FH + c0 + c4 * 4);
  }
  int nRG = (n2 + 31) >> 5;
  int cth = t & 31, rth = t >> 5;
  for (int rg = rs; rg < nRG; rg += NRS){
    int r0 = rg * 32;
    __syncthreads();
    for (int idx = t; idx < 512; idx += 256){
      int r = idx & 31, kq = idx >> 5;
      float4 v = make_float4(0.f, 0.f, 0.f, 0.f);
      if (r0 + r < n2)
        v = *(const float4*)(x + (long)S2[r0 + r] * FIN + k0 + kq * 4);
      Xl[kq * 4 + 0][r] = v.x;
      Xl[kq * 4 + 1][r] = v.y;
      Xl[kq * 4 + 2][r] = v.z;
      Xl[kq * 4 + 3][r] = v.w;
    }
    __syncthreads();
    float4 a0 = make_float4(0.f,0.f,0.f,0.f), a1 = a0, a2 = a0, a3 = a0;
    #pragma unroll 4
    for (int k = 0; k < KCK; ++k){
      float4 w  = *(const float4*)&Wl[k][cth * 4];
      float4 xv = *(const float4*)&Xl[k][rth * 4];
      a0.x += xv.x * w.x; a0.y += xv.x * w.y; a0.z += xv.x * w.z; a0.w += xv.x * w.w;
      a1.x += xv.y * w.x; a1.y += xv.y * w.y; a1.z += xv.y * w.z; a1.w += xv.y * w.w;
      a2.x += xv.z * w.x; a2.y += xv.z * w.y; a2.z += xv.z * w.z; a2.w += xv.z * w.w;
      a3.x += xv.w * w.x; a3.y += xv.w * w.y; a3.z += xv.w * w.z; a3.w += xv.w * w.w;
    }
    int rb = r0 + rth * 4;
    float* dp = hpart + ((long)kc * MAX2 + rb) * FH + c0 + cth * 4;
    if (rb + 0 < n2) *(float4*)(dp)            = a0;
    if (rb + 1 < n2) *(float4*)(dp + FH)       = a1;
    if (rb + 2 < n2) *(float4*)(dp + 2L * FH)  = a2;
    if (rb + 3 < n2) *(float4*)(dp + 3L * FH)  = a3;
  }
}

// K4: hh = sum_kc hpart ; attention scalars asrc1/adst1 (one block per S2 row)
__global__ void k_ascal(const float* __restrict__ hpart,
                        const float* __restrict__ as1, const float* __restrict__ ad1,
                        const int* __restrict__ cnt,
                        float* __restrict__ hh,
                        float* __restrict__ asrc1, float* __restrict__ adst1){
  int t = threadIdx.x, head = t >> 6;
  int n2 = cnt[1]; if (n2 > MAX2) n2 = MAX2;
  float4 a = *(const float4*)(as1 + 4 * t);
  float4 d = *(const float4*)(ad1 + 4 * t);
  for (int i = blockIdx.x; i < n2; i += gridDim.x){
    float4 s = make_float4(0.f, 0.f, 0.f, 0.f);
    #pragma unroll
    for (int kc = 0; kc < NKC; ++kc){
      float4 v = *(const float4*)(hpart + ((long)kc * MAX2 + i) * FH + 4 * t);
      s.x += v.x; s.y += v.y; s.z += v.z; s.w += v.w;
    }
    *(float4*)(hh + (long)i * FH + 4 * t) = s;
    float ss = s.x * a.x + s.y * a.y + s.z * a.z + s.w * a.w;
    float sd = s.x * d.x + s.y * d.y + s.z * d.z + s.w * d.w;
    #pragma unroll
    for (int o = 32; o; o >>= 1){ ss += __shfl_xor(ss, o, 64); sd += __shfl_xor(sd, o, 64); }
    if ((t & 63) == 0){ asrc1[i * NHEAD + head] = ss; adst1[i * NHEAD + head] = sd; }
  }
}

// K5: per S1-node (1024 threads): softmax + aggregate -> h1row -> k-split GEMV -> gb
__global__ __launch_bounds__(1024) void k_agg1(
    const float* __restrict__ hh,
    const float* __restrict__ asrc1, const float* __restrict__ adst1,
    const float* __restrict__ b1, const float* __restrict__ W2,
    const int* __restrict__ cnt, const int* __restrict__ S1,
    const int* __restrict__ slot2,
    const int* __restrict__ E1s, const int* __restrict__ E1d,
    float* __restrict__ gb){
  __shared__ int   lsrc[CAPE];
  __shared__ float ev[NHEAD][CAPE];
  __shared__ float h1row[FH];
  __shared__ float part[8][C2];
  __shared__ int   scnt;
  int t = threadIdx.x;
  int n1  = cnt[0]; if (n1  > MAX1)  n1  = MAX1;
  int nE1 = cnt[2]; if (nE1 > MAXE1) nE1 = MAXE1;
  for (int j = blockIdx.x; j < n1; j += gridDim.x){
    int s = S1[j];
    __syncthreads();
    if (t == 0) scnt = 0;
    __syncthreads();
    for (int e = t; e < nE1; e += 1024){
      if (E1d[e] == s){
        int q = atomicAdd(&scnt, 1);
        if (q < CAPE) lsrc[q] = slot2[E1s[e]];
      }
    }
    __syncthreads();
    int ce = scnt; if (ce > CAPE) ce = CAPE;
    if (t < 256){
      int w = t >> 6, lane = t & 63;
      float ad = adst1[slot2[s] * NHEAD + w];
      float m = -3.4e38f;
      for (int e = lane; e < ce; e += 64){
        float v = lrelu(asrc1[lsrc[e] * NHEAD + w] + ad);
        ev[w][e] = v;
        m = fmaxf(m, v);
      }
      #pragma unroll
      for (int o = 32; o; o >>= 1) m = fmaxf(m, __shfl_xor(m, o, 64));
      float ssum = 0.f;
      for (int e = lane; e < ce; e += 64){
        float a2 = expf(ev[w][e] - m);
        ev[w][e] = a2;
        ssum += a2;
      }
      #pragma unroll
      for (int o = 32; o; o >>= 1) ssum += __shfl_xor(ssum, o, 64);
      float inv = 1.f / (ssum + 1e-16f);
      for (int e = lane; e < ce; e += 64) ev[w][e] *= inv;
    }
    __syncthreads();
    if (t < 256){
      int hd = t >> 6;
      float4 accv = make_float4(0.f, 0.f, 0.f, 0.f);
      int e = 0;
      for (; e + 3 < ce; e += 4){
        float al0 = ev[hd][e],     al1 = ev[hd][e + 1];
        float al2 = ev[hd][e + 2], al3 = ev[hd][e + 3];
        float4 h0 = *(const float4*)(hh + (long)lsrc[e]     * FH + 4 * t);
        float4 h1 = *(const float4*)(hh + (long)lsrc[e + 1] * FH + 4 * t);
        float4 h2 = *(const float4*)(hh + (long)lsrc[e + 2] * FH + 4 * t);
        float4 h3 = *(const float4*)(hh + (long)lsrc[e + 3] * FH + 4 * t);
        accv.x += al0 * h0.x + al1 * h1.x + al2 * h2.x + al3 * h3.x;
        accv.y += al0 * h0.y + al1 * h1.y + al2 * h2.y + al3 * h3.y;
        accv.z += al0 * h0.z + al1 * h1.z + al2 * h2.z + al3 * h3.z;
        accv.w += al0 * h0.w + al1 * h1.w + al2 * h2.w + al3 * h3.w;
      }
      for (; e < ce; ++e){
        float al0 = ev[hd][e];
        float4 h0 = *(const float4*)(hh + (long)lsrc[e] * FH + 4 * t);
        accv.x += al0 * h0.x; accv.y += al0 * h0.y;
        accv.z += al0 * h0.z; accv.w += al0 * h0.w;
      }
      float4 bv = *(const float4*)(b1 + 4 * t);
      accv.x += bv.x; accv.y += bv.y; accv.z += bv.z; accv.w += bv.w;
      accv.x = accv.x > 0.f ? accv.x : 0.f;
      accv.y = accv.y > 0.f ? accv.y : 0.f;
      accv.z = accv.z > 0.f ? accv.z : 0.f;
      accv.w = accv.w > 0.f ? accv.w : 0.f;
      *(float4*)(h1row + 4 * t) = accv;
    }
    __syncthreads();
    {
      int col = t & 127, sl = t >> 7;
      const float* Wp = W2 + (long)(sl * 128) * C2 + col;
      const float* hp = h1row + sl * 128;
      float g = 0.f;
      #pragma unroll 16
      for (int k = 0; k < 128; ++k) g += hp[k] * Wp[(long)k * C2];
      part[sl][col] = g;
    }
    __syncthreads();
    if (t < C2){
      float s8 = 0.f;
      #pragma unroll
      for (int q = 0; q < 8; ++q) s8 += part[q][t];
      gb[j * C2 + t] = s8;
    }
  }
}

// K6 (512 threads): layer-2 attention + softmax + aggregate at mi, k-split MLP head
__global__ __launch_bounds__(512) void k_final(
    const int* __restrict__ mip, const int* __restrict__ cnt,
    const int* __restrict__ slot1, const int* __restrict__ E2,
    const float* __restrict__ gb,
    const float* __restrict__ as2, const float* __restrict__ ad2,
    const float* __restrict__ b2,
    const float* __restrict__ r1,
    const float* __restrict__ Wm2, const float* __restrict__ bm2,
    const float* __restrict__ Wp1, const float* __restrict__ bp1,
    const float* __restrict__ Wp2, const float* __restrict__ bp2,
    const float* __restrict__ Wp3, const float* __restrict__ bp3,
    float* __restrict__ out){
  __shared__ float al[MAXE2];
  __shared__ int   jl[MAXE2];
  __shared__ float feat[C2], r2s[C2], z1s[C2], z2s[32];
  __shared__ float p4[4][C2];
  __shared__ float p16[16][32];
  int t = threadIdx.x;
  int mi  = mip[0];
  int jmi = slot1[mi];
  int ne2 = cnt[3]; if (ne2 > MAXE2) ne2 = MAXE2;
  for (int k = t; k < ne2; k += 512) jl[k] = slot1[E2[k]];
  __syncthreads();
  int w = t >> 6, lane = t & 63;
  {
    int c = lane * 2;
    float v = gb[jmi * C2 + c] * ad2[c] + gb[jmi * C2 + c + 1] * ad2[c + 1];
    #pragma unroll
    for (int o = 32; o; o >>= 1) v += __shfl_xor(v, o, 64);
    float adv = v;
    for (int k = w; k < ne2; k += 8){
      int jj = jl[k];
      float u = gb[jj * C2 + c] * as2[c] + gb[jj * C2 + c + 1] * as2[c + 1];
      #pragma unroll
      for (int o = 32; o; o >>= 1) u += __shfl_xor(u, o, 64);
      if (lane == 0) al[k] = lrelu(u + adv);
    }
  }
  __syncthreads();
  if (t < 64){
    float m = -3.4e38f;
    for (int k = t; k < ne2; k += 64) m = fmaxf(m, al[k]);
    #pragma unroll
    for (int o = 32; o; o >>= 1) m = fmaxf(m, __shfl_xor(m, o, 64));
    float s = 0.f;
    for (int k = t; k < ne2; k += 64){
      float a2 = expf(al[k] - m);
      al[k] = a2;
      s += a2;
    }
    #pragma unroll
    for (int o = 32; o; o >>= 1) s += __shfl_xor(s, o, 64);
    float inv = 1.f / (s + 1e-16f);
    for (int k = t; k < ne2; k += 64) al[k] *= inv;
  }
  __syncthreads();
  int col = t & 127, sub = t >> 7;                 // sub in 0..3
  {
    float pr = 0.f;
    #pragma unroll 8
    for (int k = sub * 32; k < sub * 32 + 32; ++k) pr += r1[k] * Wm2[k * C2 + col];
    p4[sub][col] = pr;
    if (t < C2){
      float acc = 0.f;
      for (int k = 0; k < ne2; ++k) acc += al[k] * gb[jl[k] * C2 + t];
      float v = acc + b2[t];
      feat[t] = v > 0.f ? v : 0.f;
    }
  }
  __syncthreads();
  if (t < C2) r2s[t] = p4[0][t] + p4[1][t] + p4[2][t] + p4[3][t] + bm2[t];
  __syncthreads();
  {
    float acc = 0.f;
    #pragma unroll 8
    for (int k = sub * 64; k < sub * 64 + 64; ++k){
      float zv = (k < C2) ? feat[k] : r2s[k - C2];
      acc += zv * Wp1[k * C2 + col];
    }
    p4[sub][col] = acc;
  }
  __syncthreads();
  if (t < C2){
    float v = p4[0][t] + p4[1][t] + p4[2][t] + p4[3][t] + bp1[t];
    z1s[t] = v > 0.f ? v : 0.f;
  }
  __syncthreads();
  {
    int c2 = t & 31, sl = t >> 5;
    float acc = 0.f;
    #pragma unroll
    for (int k = sl * 8; k < sl * 8 + 8; ++k) acc += z1s[k] * Wp2[k * 32 + c2];
    p16[sl][c2] = acc;
  }
  __syncthreads();
  if (t < 32){
    float s = 0.f;
    #pragma unroll
    for (int q = 0; q < 16; ++q) s += p16[q][t];
    float v = s + bp2[t];
    z2s[t] = v > 0.f ? v : 0.f;
  }
  __syncthreads();
  if (t == 0){
    float acc = 0.f;
    for (int k = 0; k < 32; ++k) acc += z2s[k] * Wp3[k];
    out[0] = acc + bp3[0];
  }
}

extern "C" void kernel_launch(void* const* d_in, const int* in_sizes, int n_in,
                              void* d_out, int out_size, void* d_ws, size_t ws_size,
                              hipStream_t stream){
  const float* x   = (const float*)d_in[0];
  const int*   ei  = (const int*)d_in[1];
  const int*   mip = (const int*)d_in[2];
  const float* msd = (const float*)d_in[3];
  const float* Wm1 = (const float*)d_in[4];
  const float* bm1 = (const float*)d_in[5];
  const float* Wm2 = (const float*)d_in[6];
  const float* bm2 = (const float*)d_in[7];
  const float* W1  = (const float*)d_in[8];
  const float* as1 = (const float*)d_in[9];
  const float* ad1 = (const float*)d_in[10];
  const float* b1  = (const float*)d_in[11];
  const float* W2  = (const float*)d_in[12];
  const float* as2 = (const float*)d_in[13];
  const float* ad2 = (const float*)d_in[14];
  const float* b2  = (const float*)d_in[15];
  const float* Wp1 = (const float*)d_in[16];
  const float* bp1 = (const float*)d_in[17];
  const float* Wp2 = (const float*)d_in[18];
  const float* bp2 = (const float*)d_in[19];
  const float* Wp3 = (const float*)d_in[20];
  const float* bp3 = (const float*)d_in[21];
  float* out = (float*)d_out;

  char* q = (char*)d_ws;
  auto alloc = [&](size_t bytes) -> void* {
    void* r = (void*)q;
    q += (bytes + 255) & ~(size_t)255;
    return r;
  };
  int* cnt   = (int*)alloc(8 * 4);
  int* slot1 = (int*)alloc(NNODES * 4);
  int* slot2 = (int*)alloc(NNODES * 4);
  int* S1    = (int*)alloc(MAX1 * 4);
  int* S2    = (int*)alloc(MAX2 * 4);
  int* E1s   = (int*)alloc(MAXE1 * 4);
  int* E1d   = (int*)alloc(MAXE1 * 4);
  int* E2    = (int*)alloc(MAXE2 * 4);
  float* hpart = (float*)alloc((size_t)NKC * MAX2 * FH * 4);   // 41.9 MB
  float* hh    = (float*)alloc((size_t)MAX2 * FH * 4);         // 2 MB
  float* gb    = (float*)alloc(MAX1 * C2 * 4);
  float* asrc1 = (float*)alloc(MAX2 * NHEAD * 4);
  float* adst1 = (float*)alloc(MAX2 * NHEAD * 4);
  float* r1    = (float*)alloc(C2 * 4);

  k_init <<<(NNODES + 255) / 256, 256, 0, stream>>>(cnt, slot1, slot2);
  k_scan1<<<(NE_TOT + 255) / 256, 256, 0, stream>>>(ei, mip, cnt, slot1, S1, E2);
  k_scan2<<<(NE_TOT + 255) / 256, 256, 0, stream>>>(ei, cnt, slot1, slot2, S2, E1s, E1d);
  k_hh   <<<HH_GEMM_BLOCKS + 4, 256, 0, stream>>>(x, W1, msd, Wm1, bm1, cnt, S2, hpart, r1);
  k_ascal<<<128, 256, 0, stream>>>(hpart, as1, ad1, cnt, hh, asrc1, adst1);
  k_agg1 <<<32, 1024, 0, stream>>>(hh, asrc1, adst1, b1, W2, cnt, S1, slot2, E1s, E1d, gb);
  k_final<<<1, 512, 0, stream>>>(mip, cnt, slot1, E2, gb, as2, ad2, b2, r1,
                                 Wm2, bm2, Wp1, bp1, Wp2, bp2, Wp3, bp3, out);
}

// Round 8
// 73.692 us; speedup vs baseline: 1.0133x; 1.0133x over previous
//
#include <hip/hip_runtime.h>
#include <hip/hip_bf16.h>

#define NNODES 20000
#define NE_RAW 200000
#define NE_TOT 220000
#define MAX1   128
#define MAX2   512
#define MAXE1  4096
#define MAXE2  256
#define FIN    1280
#define FH     1024
#define HC     256
#define NHEAD  4
#define C2     128
#define CAPE   512
#define KCK    64       // k per chunk
#define NKC    20       // 20 x 64 = 1280
#define NRS    2        // row-splits (R6 config; R7 showed 4 regresses)
#define HH_PMD_BLOCKS 4
#define HH_GEMM_BLOCKS 320   // 20 kc x 8 ct x 2 row-splits
#define INIT_BLOCKS 79

__device__ __forceinline__ float lrelu(float x){ return x >= 0.f ? x : 0.2f * x; }

// K0: reset slot maps + counters + zero hh (atomic accumulation target)
__global__ void k_init(int* cnt, int* slot1, int* slot2, float4* hhz){
  int i = blockIdx.x * 256 + threadIdx.x;
  if (i < NNODES){ slot1[i] = -1; slot2[i] = -1; }
  if (i < 8) cnt[i] = 0;
  float4 z = make_float4(0.f, 0.f, 0.f, 0.f);
  for (int v = i; v < MAX2 * FH / 4; v += INIT_BLOCKS * 256) hhz[v] = z;
}

// K1: S1 = in-neighbors of mutation_idx (incl. self-loop), E2 = edges into mi
__global__ void k_scan1(const int* __restrict__ ei, const int* __restrict__ mip,
                        int* cnt, int* slot1, int* S1, int* E2){
  int e = blockIdx.x * 256 + threadIdx.x;
  if (e >= NE_TOT) return;
  int mi = mip[0];
  int src, dst;
  if (e < NE_RAW){ src = ei[e]; dst = ei[NE_RAW + e]; }
  else { src = e - NE_RAW; dst = src; }
  if (dst != mi) return;
  int p = atomicAdd(&cnt[3], 1);
  if (p < MAXE2) E2[p] = src;
  if (atomicCAS(&slot1[src], -1, -9) == -1){
    int idx = atomicAdd(&cnt[0], 1);
    if (idx < MAX1){ S1[idx] = src; slot1[src] = idx; }
  }
}

// K2: S2 = in-neighbors of S1; E1 = edge occurrences into S1
__global__ void k_scan2(const int* __restrict__ ei, int* cnt,
                        const int* __restrict__ slot1, int* slot2,
                        int* S2, int* E1s, int* E1d){
  int e = blockIdx.x * 256 + threadIdx.x;
  if (e >= NE_TOT) return;
  int src, dst;
  if (e < NE_RAW){ src = ei[e]; dst = ei[NE_RAW + e]; }
  else { src = e - NE_RAW; dst = src; }
  if (slot1[dst] < 0) return;
  int p = atomicAdd(&cnt[2], 1);
  if (p < MAXE1){ E1s[p] = src; E1d[p] = dst; }
  if (atomicCAS(&slot2[src], -1, -9) == -1){
    int idx = atomicAdd(&cnt[1], 1);
    if (idx < MAX2){ S2[idx] = src; slot2[src] = idx; }
  }
}

// K3: LDS-tiled pruned GEMM, accumulating DIRECTLY into hh via atomicAdd
// (no hpart round-trip). Blocks 0..3: pmd stage-1 GEMV r1 = relu(msd@Wm1+bm1).
__global__ __launch_bounds__(256) void k_hh(
    const float* __restrict__ x, const float* __restrict__ W1,
    const float* __restrict__ msd, const float* __restrict__ Wm1,
    const float* __restrict__ bm1,
    const int* __restrict__ cnt, const int* __restrict__ S2,
    float* __restrict__ hh, float* __restrict__ r1){
  int t = threadIdx.x;
  if (blockIdx.x < HH_PMD_BLOCKS){
    __shared__ float red[256];
    int b   = blockIdx.x;                    // 0..3 -> 32 cols each
    int col = b * 32 + (t & 31);
    int sl  = t >> 5;                        // 8 k-slices of 128
    float s = 0.f;
    for (int k = sl * 128; k < sl * 128 + 128; ++k)
      s += msd[k] * Wm1[k * C2 + col];
    red[t] = s;
    __syncthreads();
    if (t < 32){
      float v = 0.f;
      #pragma unroll
      for (int q = 0; q < 8; ++q) v += red[q * 32 + t];
      v += bm1[col];
      r1[col] = v > 0.f ? v : 0.f;
    }
    return;
  }
  __shared__ float Wl[KCK][128];   // 32 KB
  __shared__ float Xl[KCK][32];    // 8 KB, transposed: [k][row]
  int bid = blockIdx.x - HH_PMD_BLOCKS;
  int rs = bid & 1, ct = (bid >> 1) & 7, kc = bid >> 4;
  int k0 = kc * KCK, c0 = ct * 128;
  int n2 = cnt[1]; if (n2 > MAX2) n2 = MAX2;
  for (int idx = t; idx < 2048; idx += 256){
    int r = idx >> 5, c4 = idx & 31;
    *(float4*)&Wl[r][c4 * 4] = *(const float4*)(W1 + (long)(k0 + r) * FH + c0 + c4 * 4);
  }
  int nRG = (n2 + 31) >> 5;
  int cth = t & 31, rth = t >> 5;
  for (int rg = rs; rg < nRG; rg += NRS){
    int r0 = rg * 32;
    __syncthreads();
    for (int idx = t; idx < 512; idx += 256){
      int r = idx & 31, kq = idx >> 5;
      float4 v = make_float4(0.f, 0.f, 0.f, 0.f);
      if (r0 + r < n2)
        v = *(const float4*)(x + (long)S2[r0 + r] * FIN + k0 + kq * 4);
      Xl[kq * 4 + 0][r] = v.x;
      Xl[kq * 4 + 1][r] = v.y;
      Xl[kq * 4 + 2][r] = v.z;
      Xl[kq * 4 + 3][r] = v.w;
    }
    __syncthreads();
    float4 a0 = make_float4(0.f,0.f,0.f,0.f), a1 = a0, a2 = a0, a3 = a0;
    #pragma unroll 4
    for (int k = 0; k < KCK; ++k){
      float4 w  = *(const float4*)&Wl[k][cth * 4];
      float4 xv = *(const float4*)&Xl[k][rth * 4];
      a0.x += xv.x * w.x; a0.y += xv.x * w.y; a0.z += xv.x * w.z; a0.w += xv.x * w.w;
      a1.x += xv.y * w.x; a1.y += xv.y * w.y; a1.z += xv.y * w.z; a1.w += xv.y * w.w;
      a2.x += xv.z * w.x; a2.y += xv.z * w.y; a2.z += xv.z * w.z; a2.w += xv.z * w.w;
      a3.x += xv.w * w.x; a3.y += xv.w * w.y; a3.z += xv.w * w.z; a3.w += xv.w * w.w;
    }
    int rb = r0 + rth * 4;
    float* dp = hh + (long)rb * FH + c0 + cth * 4;
    if (rb + 0 < n2){
      atomicAdd(dp + 0, a0.x); atomicAdd(dp + 1, a0.y);
      atomicAdd(dp + 2, a0.z); atomicAdd(dp + 3, a0.w);
    }
    if (rb + 1 < n2){
      float* d1 = dp + FH;
      atomicAdd(d1 + 0, a1.x); atomicAdd(d1 + 1, a1.y);
      atomicAdd(d1 + 2, a1.z); atomicAdd(d1 + 3, a1.w);
    }
    if (rb + 2 < n2){
      float* d2 = dp + 2L * FH;
      atomicAdd(d2 + 0, a2.x); atomicAdd(d2 + 1, a2.y);
      atomicAdd(d2 + 2, a2.z); atomicAdd(d2 + 3, a2.w);
    }
    if (rb + 3 < n2){
      float* d3 = dp + 3L * FH;
      atomicAdd(d3 + 0, a3.x); atomicAdd(d3 + 1, a3.y);
      atomicAdd(d3 + 2, a3.z); atomicAdd(d3 + 3, a3.w);
    }
  }
}

// K5: per S1-node (1024 threads): inline attention dots + softmax + aggregate
//     -> h1row -> k-split GEMV -> gb   (k_ascal folded in; hh is final here)
__global__ __launch_bounds__(1024) void k_agg1(
    const float* __restrict__ hh,
    const float* __restrict__ as1, const float* __restrict__ ad1,
    const float* __restrict__ b1, const float* __restrict__ W2,
    const int* __restrict__ cnt, const int* __restrict__ S1,
    const int* __restrict__ slot2,
    const int* __restrict__ E1s, const int* __restrict__ E1d,
    float* __restrict__ gb){
  __shared__ int   lsrc[CAPE];
  __shared__ float ev[NHEAD][CAPE];
  __shared__ float adml[NHEAD];
  __shared__ float h1row[FH];
  __shared__ float part[8][C2];
  __shared__ int   scnt;
  int t = threadIdx.x;
  int n1  = cnt[0]; if (n1  > MAX1)  n1  = MAX1;
  int nE1 = cnt[2]; if (nE1 > MAXE1) nE1 = MAXE1;
  for (int j = blockIdx.x; j < n1; j += gridDim.x){
    int s = S1[j];
    __syncthreads();
    if (t == 0) scnt = 0;
    __syncthreads();
    for (int e = t; e < nE1; e += 1024){
      if (E1d[e] == s){
        int q = atomicAdd(&scnt, 1);
        if (q < CAPE) lsrc[q] = slot2[E1s[e]];
      }
    }
    __syncthreads();
    int ce = scnt; if (ce > CAPE) ce = CAPE;
    int w = t >> 6, lane = t & 63;
    // pass 1: a_dst for this node, then per-edge a_src -> logits (t<256)
    if (t < 256){
      float4 a = *(const float4*)(as1 + 4 * t);
      float4 d = *(const float4*)(ad1 + 4 * t);
      {
        float4 hv = *(const float4*)(hh + (long)slot2[s] * FH + 4 * t);
        float sd = hv.x * d.x + hv.y * d.y + hv.z * d.z + hv.w * d.w;
        #pragma unroll
        for (int o = 32; o; o >>= 1) sd += __shfl_xor(sd, o, 64);
        if (lane == 0) adml[w] = sd;
      }
      int e = 0;
      for (; e + 1 < ce; e += 2){
        float4 h0 = *(const float4*)(hh + (long)lsrc[e]     * FH + 4 * t);
        float4 h1 = *(const float4*)(hh + (long)lsrc[e + 1] * FH + 4 * t);
        float s0 = h0.x * a.x + h0.y * a.y + h0.z * a.z + h0.w * a.w;
        float s1 = h1.x * a.x + h1.y * a.y + h1.z * a.z + h1.w * a.w;
        #pragma unroll
        for (int o = 32; o; o >>= 1){
          s0 += __shfl_xor(s0, o, 64);
          s1 += __shfl_xor(s1, o, 64);
        }
        if (lane == 0){ ev[w][e] = s0; ev[w][e + 1] = s1; }
      }
      if (e < ce){
        float4 h0 = *(const float4*)(hh + (long)lsrc[e] * FH + 4 * t);
        float s0 = h0.x * a.x + h0.y * a.y + h0.z * a.z + h0.w * a.w;
        #pragma unroll
        for (int o = 32; o; o >>= 1) s0 += __shfl_xor(s0, o, 64);
        if (lane == 0) ev[w][e] = s0;
      }
    }
    __syncthreads();
    // softmax over logits (t<256; one wave per head)
    if (t < 256){
      float adv = adml[w];
      float m = -3.4e38f;
      for (int e = lane; e < ce; e += 64){
        float v = lrelu(ev[w][e] + adv);
        ev[w][e] = v;
        m = fmaxf(m, v);
      }
      #pragma unroll
      for (int o = 32; o; o >>= 1) m = fmaxf(m, __shfl_xor(m, o, 64));
      float ssum = 0.f;
      for (int e = lane; e < ce; e += 64){
        float a2 = expf(ev[w][e] - m);
        ev[w][e] = a2;
        ssum += a2;
      }
      #pragma unroll
      for (int o = 32; o; o >>= 1) ssum += __shfl_xor(ssum, o, 64);
      float inv = 1.f / (ssum + 1e-16f);
      for (int e = lane; e < ce; e += 64) ev[w][e] *= inv;
    }
    __syncthreads();
    // aggregate (rows now L1/L2-hot from pass 1)
    if (t < 256){
      int hd = t >> 6;
      float4 accv = make_float4(0.f, 0.f, 0.f, 0.f);
      int e = 0;
      for (; e + 3 < ce; e += 4){
        float al0 = ev[hd][e],     al1 = ev[hd][e + 1];
        float al2 = ev[hd][e + 2], al3 = ev[hd][e + 3];
        float4 h0 = *(const float4*)(hh + (long)lsrc[e]     * FH + 4 * t);
        float4 h1 = *(const float4*)(hh + (long)lsrc[e + 1] * FH + 4 * t);
        float4 h2 = *(const float4*)(hh + (long)lsrc[e + 2] * FH + 4 * t);
        float4 h3 = *(const float4*)(hh + (long)lsrc[e + 3] * FH + 4 * t);
        accv.x += al0 * h0.x + al1 * h1.x + al2 * h2.x + al3 * h3.x;
        accv.y += al0 * h0.y + al1 * h1.y + al2 * h2.y + al3 * h3.y;
        accv.z += al0 * h0.z + al1 * h1.z + al2 * h2.z + al3 * h3.z;
        accv.w += al0 * h0.w + al1 * h1.w + al2 * h2.w + al3 * h3.w;
      }
      for (; e < ce; ++e){
        float al0 = ev[hd][e];
        float4 h0 = *(const float4*)(hh + (long)lsrc[e] * FH + 4 * t);
        accv.x += al0 * h0.x; accv.y += al0 * h0.y;
        accv.z += al0 * h0.z; accv.w += al0 * h0.w;
      }
      float4 bv = *(const float4*)(b1 + 4 * t);
      accv.x += bv.x; accv.y += bv.y; accv.z += bv.z; accv.w += bv.w;
      accv.x = accv.x > 0.f ? accv.x : 0.f;
      accv.y = accv.y > 0.f ? accv.y : 0.f;
      accv.z = accv.z > 0.f ? accv.z : 0.f;
      accv.w = accv.w > 0.f ? accv.w : 0.f;
      *(float4*)(h1row + 4 * t) = accv;
    }
    __syncthreads();
    // GEMV h1row @ W2: 128 cols x 8 k-slices of 128 (all 1024 threads)
    {
      int col = t & 127, sl = t >> 7;
      const float* Wp = W2 + (long)(sl * 128) * C2 + col;
      const float* hp = h1row + sl * 128;
      float g = 0.f;
      #pragma unroll 16
      for (int k = 0; k < 128; ++k) g += hp[k] * Wp[(long)k * C2];
      part[sl][col] = g;
    }
    __syncthreads();
    if (t < C2){
      float s8 = 0.f;
      #pragma unroll
      for (int q = 0; q < 8; ++q) s8 += part[q][t];
      gb[j * C2 + t] = s8;
    }
  }
}

// K6 (512 threads): layer-2 attention + softmax + aggregate at mi, k-split MLP head
__global__ __launch_bounds__(512) void k_final(
    const int* __restrict__ mip, const int* __restrict__ cnt,
    const int* __restrict__ slot1, const int* __restrict__ E2,
    const float* __restrict__ gb,
    const float* __restrict__ as2, const float* __restrict__ ad2,
    const float* __restrict__ b2,
    const float* __restrict__ r1,
    const float* __restrict__ Wm2, const float* __restrict__ bm2,
    const float* __restrict__ Wp1, const float* __restrict__ bp1,
    const float* __restrict__ Wp2, const float* __restrict__ bp2,
    const float* __restrict__ Wp3, const float* __restrict__ bp3,
    float* __restrict__ out){
  __shared__ float al[MAXE2];
  __shared__ int   jl[MAXE2];
  __shared__ float feat[C2], r2s[C2], z1s[C2], z2s[32];
  __shared__ float p4[4][C2];
  __shared__ float p16[16][32];
  int t = threadIdx.x;
  int mi  = mip[0];
  int jmi = slot1[mi];
  int ne2 = cnt[3]; if (ne2 > MAXE2) ne2 = MAXE2;
  for (int k = t; k < ne2; k += 512) jl[k] = slot1[E2[k]];
  __syncthreads();
  int w = t >> 6, lane = t & 63;
  {
    int c = lane * 2;
    float v = gb[jmi * C2 + c] * ad2[c] + gb[jmi * C2 + c + 1] * ad2[c + 1];
    #pragma unroll
    for (int o = 32; o; o >>= 1) v += __shfl_xor(v, o, 64);
    float adv = v;
    for (int k = w; k < ne2; k += 8){
      int jj = jl[k];
      float u = gb[jj * C2 + c] * as2[c] + gb[jj * C2 + c + 1] * as2[c + 1];
      #pragma unroll
      for (int o = 32; o; o >>= 1) u += __shfl_xor(u, o, 64);
      if (lane == 0) al[k] = lrelu(u + adv);
    }
  }
  __syncthreads();
  if (t < 64){
    float m = -3.4e38f;
    for (int k = t; k < ne2; k += 64) m = fmaxf(m, al[k]);
    #pragma unroll
    for (int o = 32; o; o >>= 1) m = fmaxf(m, __shfl_xor(m, o, 64));
    float s = 0.f;
    for (int k = t; k < ne2; k += 64){
      float a2 = expf(al[k] - m);
      al[k] = a2;
      s += a2;
    }
    #pragma unroll
    for (int o = 32; o; o >>= 1) s += __shfl_xor(s, o, 64);
    float inv = 1.f / (s + 1e-16f);
    for (int k = t; k < ne2; k += 64) al[k] *= inv;
  }
  __syncthreads();
  int col = t & 127, sub = t >> 7;                 // sub in 0..3
  {
    float pr = 0.f;
    #pragma unroll 8
    for (int k = sub * 32; k < sub * 32 + 32; ++k) pr += r1[k] * Wm2[k * C2 + col];
    p4[sub][col] = pr;
    if (t < C2){
      float acc = 0.f;
      for (int k = 0; k < ne2; ++k) acc += al[k] * gb[jl[k] * C2 + t];
      float v = acc + b2[t];
      feat[t] = v > 0.f ? v : 0.f;
    }
  }
  __syncthreads();
  if (t < C2) r2s[t] = p4[0][t] + p4[1][t] + p4[2][t] + p4[3][t] + bm2[t];
  __syncthreads();
  {
    float acc = 0.f;
    #pragma unroll 8
    for (int k = sub * 64; k < sub * 64 + 64; ++k){
      float zv = (k < C2) ? feat[k] : r2s[k - C2];
      acc += zv * Wp1[k * C2 + col];
    }
    p4[sub][col] = acc;
  }
  __syncthreads();
  if (t < C2){
    float v = p4[0][t] + p4[1][t] + p4[2][t] + p4[3][t] + bp1[t];
    z1s[t] = v > 0.f ? v : 0.f;
  }
  __syncthreads();
  {
    int c2 = t & 31, sl = t >> 5;
    float acc = 0.f;
    #pragma unroll
    for (int k = sl * 8; k < sl * 8 + 8; ++k) acc += z1s[k] * Wp2[k * 32 + c2];
    p16[sl][c2] = acc;
  }
  __syncthreads();
  if (t < 32){
    float s = 0.f;
    #pragma unroll
    for (int q = 0; q < 16; ++q) s += p16[q][t];
    float v = s + bp2[t];
    z2s[t] = v > 0.f ? v : 0.f;
  }
  __syncthreads();
  if (t == 0){
    float acc = 0.f;
    for (int k = 0; k < 32; ++k) acc += z2s[k] * Wp3[k];
    out[0] = acc + bp3[0];
  }
}

extern "C" void kernel_launch(void* const* d_in, const int* in_sizes, int n_in,
                              void* d_out, int out_size, void* d_ws, size_t ws_size,
                              hipStream_t stream){
  const float* x   = (const float*)d_in[0];
  const int*   ei  = (const int*)d_in[1];
  const int*   mip = (const int*)d_in[2];
  const float* msd = (const float*)d_in[3];
  const float* Wm1 = (const float*)d_in[4];
  const float* bm1 = (const float*)d_in[5];
  const float* Wm2 = (const float*)d_in[6];
  const float* bm2 = (const float*)d_in[7];
  const float* W1  = (const float*)d_in[8];
  const float* as1 = (const float*)d_in[9];
  const float* ad1 = (const float*)d_in[10];
  const float* b1  = (const float*)d_in[11];
  const float* W2  = (const float*)d_in[12];
  const float* as2 = (const float*)d_in[13];
  const float* ad2 = (const float*)d_in[14];
  const float* b2  = (const float*)d_in[15];
  const float* Wp1 = (const float*)d_in[16];
  const float* bp1 = (const float*)d_in[17];
  const float* Wp2 = (const float*)d_in[18];
  const float* bp2 = (const float*)d_in[19];
  const float* Wp3 = (const float*)d_in[20];
  const float* bp3 = (const float*)d_in[21];
  float* out = (float*)d_out;

  char* q = (char*)d_ws;
  auto alloc = [&](size_t bytes) -> void* {
    void* r = (void*)q;
    q += (bytes + 255) & ~(size_t)255;
    return r;
  };
  int* cnt   = (int*)alloc(8 * 4);
  int* slot1 = (int*)alloc(NNODES * 4);
  int* slot2 = (int*)alloc(NNODES * 4);
  int* S1    = (int*)alloc(MAX1 * 4);
  int* S2    = (int*)alloc(MAX2 * 4);
  int* E1s   = (int*)alloc(MAXE1 * 4);
  int* E1d   = (int*)alloc(MAXE1 * 4);
  int* E2    = (int*)alloc(MAXE2 * 4);
  float* hh  = (float*)alloc((size_t)MAX2 * FH * 4);    // 2 MB, atomically accumulated
  float* gb  = (float*)alloc(MAX1 * C2 * 4);
  float* r1  = (float*)alloc(C2 * 4);

  k_init <<<INIT_BLOCKS, 256, 0, stream>>>(cnt, slot1, slot2, (float4*)hh);
  k_scan1<<<(NE_TOT + 255) / 256, 256, 0, stream>>>(ei, mip, cnt, slot1, S1, E2);
  k_scan2<<<(NE_TOT + 255) / 256, 256, 0, stream>>>(ei, cnt, slot1, slot2, S2, E1s, E1d);
  k_hh   <<<HH_PMD_BLOCKS + HH_GEMM_BLOCKS, 256, 0, stream>>>(x, W1, msd, Wm1, bm1, cnt, S2, hh, r1);
  k_agg1 <<<32, 1024, 0, stream>>>(hh, as1, ad1, b1, W2, cnt, S1, slot2, E1s, E1d, gb);
  k_final<<<1, 512, 0, stream>>>(mip, cnt, slot1, E2, gb, as2, ad2, b2, r1,
                                 Wm2, bm2, Wp1, bp1, Wp2, bp2, Wp3, bp3, out);
}

// Round 9
// 68.973 us; speedup vs baseline: 1.0826x; 1.0684x over previous
//
#include <hip/hip_runtime.h>
#include <hip/hip_bf16.h>

#define NNODES 20000
#define NE_RAW 200000
#define NE_TOT 220000
#define MAX1   128
#define MAXE1  4096
#define MAXE2  256
#define FIN    1280
#define FH     1024
#define NHEAD  4
#define C2     128
#define CAPE   512
#define KCK    64
#define NKC    20          // 20 x 64 = 1280
#define INIT_B 79
#define A_B    160         // 160 blocks x 8 rows = 1280 rows of W1
#define PMD_B  4
#define D_B    160         // 20 kc x 8 ct

__device__ __forceinline__ float lrelu(float x){ return x >= 0.f ? x : 0.2f * x; }

// K0: init slot1/cnt  |  A: w_att[k][0..3]=W1@as1, [4..7]=W1@ad1  |  pmd GEMV
__global__ __launch_bounds__(256) void k_init_a(
    const float* __restrict__ W1, const float* __restrict__ as1,
    const float* __restrict__ ad1,
    const float* __restrict__ msd, const float* __restrict__ Wm1,
    const float* __restrict__ bm1,
    int* cnt, int* slot1, float* __restrict__ w_att, float* __restrict__ r1){
  int t = threadIdx.x, b = blockIdx.x;
  if (b < INIT_B){
    int i = b * 256 + t;
    if (i < NNODES) slot1[i] = -1;
    if (i < 8) cnt[i] = 0;
    return;
  }
  if (b >= INIT_B + A_B){                      // pmd stage-1 GEMV
    __shared__ float red[256];
    int pb  = b - INIT_B - A_B;                // 0..3
    int col = pb * 32 + (t & 31);
    int sl  = t >> 5;
    float s = 0.f;
    for (int k = sl * 128; k < sl * 128 + 128; ++k)
      s += msd[k] * Wm1[k * C2 + col];
    red[t] = s;
    __syncthreads();
    if (t < 32){
      float v = 0.f;
      #pragma unroll
      for (int q = 0; q < 8; ++q) v += red[q * 32 + t];
      v += bm1[col];
      r1[col] = v > 0.f ? v : 0.f;
    }
    return;
  }
  // A: 8 rows of W1 per block
  __shared__ float red[4][8];
  int kbase = (b - INIT_B) * 8;
  int w = t >> 6, lane = t & 63;
  float av0 = as1[t], av1 = as1[t + 256], av2 = as1[t + 512], av3 = as1[t + 768];
  float dv0 = ad1[t], dv1 = ad1[t + 256], dv2 = ad1[t + 512], dv3 = ad1[t + 768];
  for (int rr = 0; rr < 8; ++rr){
    int k = kbase + rr;
    const float* Wr = W1 + (long)k * FH;
    float w0 = Wr[t], w1 = Wr[t + 256], w2 = Wr[t + 512], w3 = Wr[t + 768];
    float v[8] = { w0*av0, w1*av1, w2*av2, w3*av3, w0*dv0, w1*dv1, w2*dv2, w3*dv3 };
    #pragma unroll
    for (int q = 0; q < 8; ++q){
      float s = v[q];
      #pragma unroll
      for (int o = 32; o; o >>= 1) s += __shfl_xor(s, o, 64);
      if (lane == 0) red[w][q] = s;
      __syncthreads();
      if (t == 0) w_att[k * 8 + q] = red[0][q] + red[1][q] + red[2][q] + red[3][q];
      __syncthreads();
    }
  }
}

// K1: S1 = in-neighbors of mi (incl. self-loop), E2 = edge occurrences into mi
__global__ void k_scan1(const int* __restrict__ ei, const int* __restrict__ mip,
                        int* cnt, int* slot1, int* S1, int* E2){
  int e0 = (blockIdx.x * 256 + threadIdx.x) * 4;
  if (e0 >= NE_TOT) return;
  int mi = mip[0];
  int s[4], d[4], n = 0;
  if (e0 + 3 < NE_RAW){
    int4 s4 = *(const int4*)(ei + e0);
    int4 d4 = *(const int4*)(ei + NE_RAW + e0);
    s[0]=s4.x; s[1]=s4.y; s[2]=s4.z; s[3]=s4.w;
    d[0]=d4.x; d[1]=d4.y; d[2]=d4.z; d[3]=d4.w;
    n = 4;
  } else {
    for (int q = 0; q < 4; ++q){
      int e = e0 + q;
      if (e >= NE_TOT) break;
      if (e < NE_RAW){ s[n] = ei[e]; d[n] = ei[NE_RAW + e]; }
      else { s[n] = e - NE_RAW; d[n] = s[n]; }
      ++n;
    }
  }
  for (int q = 0; q < n; ++q){
    if (d[q] != mi) continue;
    int p = atomicAdd(&cnt[3], 1);
    if (p < MAXE2) E2[p] = s[q];
    if (atomicCAS(&slot1[s[q]], -1, -9) == -1){
      int idx = atomicAdd(&cnt[0], 1);
      if (idx < MAX1){ S1[idx] = s[q]; slot1[s[q]] = idx; }
    }
  }
}

// K2: E1 = edge occurrences into S1 (src node ids kept raw; no slot2 needed)
__global__ void k_scan2(const int* __restrict__ ei, int* cnt,
                        const int* __restrict__ slot1, int* E1s, int* E1d){
  int e0 = (blockIdx.x * 256 + threadIdx.x) * 4;
  if (e0 >= NE_TOT) return;
  int s[4], d[4], n = 0;
  if (e0 + 3 < NE_RAW){
    int4 s4 = *(const int4*)(ei + e0);
    int4 d4 = *(const int4*)(ei + NE_RAW + e0);
    s[0]=s4.x; s[1]=s4.y; s[2]=s4.z; s[3]=s4.w;
    d[0]=d4.x; d[1]=d4.y; d[2]=d4.z; d[3]=d4.w;
    n = 4;
  } else {
    for (int q = 0; q < 4; ++q){
      int e = e0 + q;
      if (e >= NE_TOT) break;
      if (e < NE_RAW){ s[n] = ei[e]; d[n] = ei[NE_RAW + e]; }
      else { s[n] = e - NE_RAW; d[n] = s[n]; }
      ++n;
    }
  }
  for (int q = 0; q < n; ++q){
    if (slot1[d[q]] < 0) continue;
    int p = atomicAdd(&cnt[2], 1);
    if (p < MAXE1){ E1s[p] = s[q]; E1d[p] = d[q]; }
  }
}

// K3 (BC): per S1 node: per-edge logits (x[src]·w_att), softmax, aggregate
//          X1[j][h][:] = sum_e alpha[h][e] * x[src_e][:]
__global__ __launch_bounds__(256) void k_bc(
    const float* __restrict__ x, const float* __restrict__ w_att,
    const int* __restrict__ cnt, const int* __restrict__ S1,
    const int* __restrict__ E1s, const int* __restrict__ E1d,
    float* __restrict__ X1){
  __shared__ int   lsrc[CAPE];
  __shared__ float ev[NHEAD][CAPE];
  __shared__ float adml[NHEAD];
  __shared__ float redl[4][4];
  __shared__ int   scnt;
  int t = threadIdx.x, w = t >> 6, lane = t & 63;
  int n1  = cnt[0]; if (n1  > MAX1)  n1  = MAX1;
  int nE1 = cnt[2]; if (nE1 > MAXE1) nE1 = MAXE1;
  for (int j = blockIdx.x; j < n1; j += gridDim.x){
    int s = S1[j];
    __syncthreads();
    if (t == 0) scnt = 0;
    __syncthreads();
    for (int e = t; e < nE1; e += 256){
      if (E1d[e] == s){
        int q = atomicAdd(&scnt, 1);
        if (q < CAPE) lsrc[q] = E1s[e];
      }
    }
    __syncthreads();
    int ce = scnt; if (ce > CAPE) ce = CAPE;
    // a_dst for this node (block-wide dot over 1280)
    {
      const float* xs = x + (long)s * FIN;
      float a0=0.f, a1=0.f, a2=0.f, a3=0.f;
      #pragma unroll
      for (int i = 0; i < 5; ++i){
        int k = t + 256 * i;
        float xv = xs[k];
        float4 wd = *(const float4*)(w_att + k * 8 + 4);
        a0 += xv * wd.x; a1 += xv * wd.y; a2 += xv * wd.z; a3 += xv * wd.w;
      }
      float v[4] = { a0, a1, a2, a3 };
      #pragma unroll
      for (int q = 0; q < 4; ++q){
        float sv = v[q];
        #pragma unroll
        for (int o = 32; o; o >>= 1) sv += __shfl_xor(sv, o, 64);
        if (lane == 0) redl[w][q] = sv;
      }
      __syncthreads();
      if (t < 4) adml[t] = redl[0][t] + redl[1][t] + redl[2][t] + redl[3][t];
      __syncthreads();
    }
    // per-edge a_src (wave w handles edges e = w, w+4, ...)
    for (int e = w; e < ce; e += 4){
      const float* xe = x + (long)lsrc[e] * FIN;
      float b0=0.f, b1v=0.f, b2v=0.f, b3v=0.f;
      #pragma unroll 4
      for (int i = 0; i < 20; ++i){
        int k = lane + 64 * i;
        float xv = xe[k];
        float4 ws = *(const float4*)(w_att + k * 8);
        b0 += xv * ws.x; b1v += xv * ws.y; b2v += xv * ws.z; b3v += xv * ws.w;
      }
      #pragma unroll
      for (int o = 32; o; o >>= 1){
        b0  += __shfl_xor(b0, o, 64);  b1v += __shfl_xor(b1v, o, 64);
        b2v += __shfl_xor(b2v, o, 64); b3v += __shfl_xor(b3v, o, 64);
      }
      if (lane == 0){ ev[0][e]=b0; ev[1][e]=b1v; ev[2][e]=b2v; ev[3][e]=b3v; }
    }
    __syncthreads();
    // softmax per head (wave w = head w)
    {
      float ad = adml[w];
      float m = -3.4e38f;
      for (int e = lane; e < ce; e += 64){
        float v = lrelu(ev[w][e] + ad);
        ev[w][e] = v;
        m = fmaxf(m, v);
      }
      #pragma unroll
      for (int o = 32; o; o >>= 1) m = fmaxf(m, __shfl_xor(m, o, 64));
      float ssum = 0.f;
      for (int e = lane; e < ce; e += 64){
        float a2 = expf(ev[w][e] - m);
        ev[w][e] = a2;
        ssum += a2;
      }
      #pragma unroll
      for (int o = 32; o; o >>= 1) ssum += __shfl_xor(ssum, o, 64);
      float inv = 1.f / (ssum + 1e-16f);
      for (int e = lane; e < ce; e += 64) ev[w][e] *= inv;
    }
    __syncthreads();
    // aggregate x rows per head: wave w = head w, lane covers k = lane + 64i
    {
      float acc[20];
      #pragma unroll
      for (int i = 0; i < 20; ++i) acc[i] = 0.f;
      for (int e = 0; e < ce; ++e){
        float al = ev[w][e];
        const float* xe = x + (long)lsrc[e] * FIN;
        #pragma unroll
        for (int i = 0; i < 20; ++i) acc[i] += al * xe[lane + 64 * i];
      }
      float* X1p = X1 + ((long)j * NHEAD + w) * FIN;
      #pragma unroll
      for (int i = 0; i < 20; ++i) X1p[lane + 64 * i] = acc[i];
    }
    __syncthreads();
  }
}

// K4 (D): tiny GEMM h1-partials: hpart[kc][j][ct*128+col] = X1[j][head(ct)][kc]@W1
__global__ __launch_bounds__(256) void k_d(
    const float* __restrict__ X1, const float* __restrict__ W1,
    const int* __restrict__ cnt, float* __restrict__ hpart){
  __shared__ float Wl[KCK][128];   // 32 KB
  __shared__ float Xl[KCK][16];    // 4 KB
  int t = threadIdx.x, bid = blockIdx.x;
  int ct = bid & 7, kc = bid >> 3;
  int head = ct >> 1;
  int k0 = kc * KCK, c0 = ct * 128;
  int n1 = cnt[0]; if (n1 > MAX1) n1 = MAX1;
  for (int idx = t; idx < 2048; idx += 256){
    int r = idx >> 5, c4 = idx & 31;
    *(float4*)&Wl[r][c4 * 4] = *(const float4*)(W1 + (long)(k0 + r) * FH + c0 + c4 * 4);
  }
  int nRG = (n1 + 15) >> 4;
  int cth = t & 31, rth = t >> 5;
  for (int rg = 0; rg < nRG; ++rg){
    int r0 = rg * 16;
    __syncthreads();
    {
      int r = t & 15, kq = t >> 4;   // 256 threads = 16 rows x 16 f4-groups
      float4 v = make_float4(0.f, 0.f, 0.f, 0.f);
      if (r0 + r < n1)
        v = *(const float4*)(X1 + ((long)(r0 + r) * NHEAD + head) * FIN + k0 + kq * 4);
      Xl[kq * 4 + 0][r] = v.x;
      Xl[kq * 4 + 1][r] = v.y;
      Xl[kq * 4 + 2][r] = v.z;
      Xl[kq * 4 + 3][r] = v.w;
    }
    __syncthreads();
    float4 A0 = make_float4(0.f,0.f,0.f,0.f), A1 = A0;
    #pragma unroll 4
    for (int k = 0; k < KCK; ++k){
      float4 wv = *(const float4*)&Wl[k][cth * 4];
      float x0 = Xl[k][rth * 2], x1 = Xl[k][rth * 2 + 1];
      A0.x += x0 * wv.x; A0.y += x0 * wv.y; A0.z += x0 * wv.z; A0.w += x0 * wv.w;
      A1.x += x1 * wv.x; A1.y += x1 * wv.y; A1.z += x1 * wv.z; A1.w += x1 * wv.w;
    }
    int rb = r0 + rth * 2;
    float* dp = hpart + ((long)kc * MAX1 + rb) * FH + c0 + cth * 4;
    if (rb < n1)     *(float4*)(dp)      = A0;
    if (rb + 1 < n1) *(float4*)(dp + FH) = A1;
  }
}

// K5 (E): per S1 node: h1 = relu(sum_kc hpart + b1) -> k-split GEMV @ W2 -> gb
__global__ __launch_bounds__(1024) void k_e(
    const float* __restrict__ hpart, const float* __restrict__ b1,
    const float* __restrict__ W2, const int* __restrict__ cnt,
    float* __restrict__ gb){
  __shared__ float h1row[FH];
  __shared__ float part[8][C2];
  int t = threadIdx.x;
  int n1 = cnt[0]; if (n1 > MAX1) n1 = MAX1;
  for (int j = blockIdx.x; j < n1; j += gridDim.x){
    __syncthreads();
    if (t < 256){
      float4 s = make_float4(0.f, 0.f, 0.f, 0.f);
      #pragma unroll
      for (int kc = 0; kc < NKC; ++kc){
        float4 v = *(const float4*)(hpart + ((long)kc * MAX1 + j) * FH + 4 * t);
        s.x += v.x; s.y += v.y; s.z += v.z; s.w += v.w;
      }
      float4 bv = *(const float4*)(b1 + 4 * t);
      s.x += bv.x; s.y += bv.y; s.z += bv.z; s.w += bv.w;
      s.x = s.x > 0.f ? s.x : 0.f;
      s.y = s.y > 0.f ? s.y : 0.f;
      s.z = s.z > 0.f ? s.z : 0.f;
      s.w = s.w > 0.f ? s.w : 0.f;
      *(float4*)(h1row + 4 * t) = s;
    }
    __syncthreads();
    {
      int col = t & 127, sl = t >> 7;
      const float* Wp = W2 + (long)(sl * 128) * C2 + col;
      const float* hp = h1row + sl * 128;
      float g = 0.f;
      #pragma unroll 16
      for (int k = 0; k < 128; ++k) g += hp[k] * Wp[(long)k * C2];
      part[sl][col] = g;
    }
    __syncthreads();
    if (t < C2){
      float s8 = 0.f;
      #pragma unroll
      for (int q = 0; q < 8; ++q) s8 += part[q][t];
      gb[j * C2 + t] = s8;
    }
  }
}

// K6 (512 threads): layer-2 attention + softmax + aggregate at mi, k-split MLP head
__global__ __launch_bounds__(512) void k_final(
    const int* __restrict__ mip, const int* __restrict__ cnt,
    const int* __restrict__ slot1, const int* __restrict__ E2,
    const float* __restrict__ gb,
    const float* __restrict__ as2, const float* __restrict__ ad2,
    const float* __restrict__ b2,
    const float* __restrict__ r1,
    const float* __restrict__ Wm2, const float* __restrict__ bm2,
    const float* __restrict__ Wp1, const float* __restrict__ bp1,
    const float* __restrict__ Wp2, const float* __restrict__ bp2,
    const float* __restrict__ Wp3, const float* __restrict__ bp3,
    float* __restrict__ out){
  __shared__ float al[MAXE2];
  __shared__ int   jl[MAXE2];
  __shared__ float feat[C2], r2s[C2], z1s[C2], z2s[32];
  __shared__ float p4[4][C2];
  __shared__ float p16[16][32];
  int t = threadIdx.x;
  int mi  = mip[0];
  int jmi = slot1[mi];
  int ne2 = cnt[3]; if (ne2 > MAXE2) ne2 = MAXE2;
  for (int k = t; k < ne2; k += 512) jl[k] = slot1[E2[k]];
  __syncthreads();
  int w = t >> 6, lane = t & 63;
  {
    int c = lane * 2;
    float v = gb[jmi * C2 + c] * ad2[c] + gb[jmi * C2 + c + 1] * ad2[c + 1];
    #pragma unroll
    for (int o = 32; o; o >>= 1) v += __shfl_xor(v, o, 64);
    float adv = v;
    for (int k = w; k < ne2; k += 8){
      int jj = jl[k];
      float u = gb[jj * C2 + c] * as2[c] + gb[jj * C2 + c + 1] * as2[c + 1];
      #pragma unroll
      for (int o = 32; o; o >>= 1) u += __shfl_xor(u, o, 64);
      if (lane == 0) al[k] = lrelu(u + adv);
    }
  }
  __syncthreads();
  if (t < 64){
    float m = -3.4e38f;
    for (int k = t; k < ne2; k += 64) m = fmaxf(m, al[k]);
    #pragma unroll
    for (int o = 32; o; o >>= 1) m = fmaxf(m, __shfl_xor(m, o, 64));
    float s = 0.f;
    for (int k = t; k < ne2; k += 64){
      float a2 = expf(al[k] - m);
      al[k] = a2;
      s += a2;
    }
    #pragma unroll
    for (int o = 32; o; o >>= 1) s += __shfl_xor(s, o, 64);
    float inv = 1.f / (s + 1e-16f);
    for (int k = t; k < ne2; k += 64) al[k] *= inv;
  }
  __syncthreads();
  int col = t & 127, sub = t >> 7;
  {
    float pr = 0.f;
    #pragma unroll 8
    for (int k = sub * 32; k < sub * 32 + 32; ++k) pr += r1[k] * Wm2[k * C2 + col];
    p4[sub][col] = pr;
    if (t < C2){
      float acc = 0.f;
      for (int k = 0; k < ne2; ++k) acc += al[k] * gb[jl[k] * C2 + t];
      float v = acc + b2[t];
      feat[t] = v > 0.f ? v : 0.f;
    }
  }
  __syncthreads();
  if (t < C2) r2s[t] = p4[0][t] + p4[1][t] + p4[2][t] + p4[3][t] + bm2[t];
  __syncthreads();
  {
    float acc = 0.f;
    #pragma unroll 8
    for (int k = sub * 64; k < sub * 64 + 64; ++k){
      float zv = (k < C2) ? feat[k] : r2s[k - C2];
      acc += zv * Wp1[k * C2 + col];
    }
    p4[sub][col] = acc;
  }
  __syncthreads();
  if (t < C2){
    float v = p4[0][t] + p4[1][t] + p4[2][t] + p4[3][t] + bp1[t];
    z1s[t] = v > 0.f ? v : 0.f;
  }
  __syncthreads();
  {
    int c2 = t & 31, sl = t >> 5;
    float acc = 0.f;
    #pragma unroll
    for (int k = sl * 8; k < sl * 8 + 8; ++k) acc += z1s[k] * Wp2[k * 32 + c2];
    p16[sl][c2] = acc;
  }
  __syncthreads();
  if (t < 32){
    float s = 0.f;
    #pragma unroll
    for (int q = 0; q < 16; ++q) s += p16[q][t];
    float v = s + bp2[t];
    z2s[t] = v > 0.f ? v : 0.f;
  }
  __syncthreads();
  if (t == 0){
    float acc = 0.f;
    for (int k = 0; k < 32; ++k) acc += z2s[k] * Wp3[k];
    out[0] = acc + bp3[0];
  }
}

extern "C" void kernel_launch(void* const* d_in, const int* in_sizes, int n_in,
                              void* d_out, int out_size, void* d_ws, size_t ws_size,
                              hipStream_t stream){
  const float* x   = (const float*)d_in[0];
  const int*   ei  = (const int*)d_in[1];
  const int*   mip = (const int*)d_in[2];
  const float* msd = (const float*)d_in[3];
  const float* Wm1 = (const float*)d_in[4];
  const float* bm1 = (const float*)d_in[5];
  const float* Wm2 = (const float*)d_in[6];
  const float* bm2 = (const float*)d_in[7];
  const float* W1  = (const float*)d_in[8];
  const float* as1 = (const float*)d_in[9];
  const float* ad1 = (const float*)d_in[10];
  const float* b1  = (const float*)d_in[11];
  const float* W2  = (const float*)d_in[12];
  const float* as2 = (const float*)d_in[13];
  const float* ad2 = (const float*)d_in[14];
  const float* b2  = (const float*)d_in[15];
  const float* Wp1 = (const float*)d_in[16];
  const float* bp1 = (const float*)d_in[17];
  const float* Wp2 = (const float*)d_in[18];
  const float* bp2 = (const float*)d_in[19];
  const float* Wp3 = (const float*)d_in[20];
  const float* bp3 = (const float*)d_in[21];
  float* out = (float*)d_out;

  char* q = (char*)d_ws;
  auto alloc = [&](size_t bytes) -> void* {
    void* r = (void*)q;
    q += (bytes + 255) & ~(size_t)255;
    return r;
  };
  int* cnt   = (int*)alloc(8 * 4);
  int* slot1 = (int*)alloc(NNODES * 4);
  int* S1    = (int*)alloc(MAX1 * 4);
  int* E1s   = (int*)alloc(MAXE1 * 4);
  int* E1d   = (int*)alloc(MAXE1 * 4);
  int* E2    = (int*)alloc(MAXE2 * 4);
  float* w_att = (float*)alloc((size_t)FIN * 8 * 4);                 // 40 KB
  float* X1    = (float*)alloc((size_t)MAX1 * NHEAD * FIN * 4);      // 2.6 MB
  float* hpart = (float*)alloc((size_t)NKC * MAX1 * FH * 4);         // 10.5 MB
  float* gb    = (float*)alloc(MAX1 * C2 * 4);
  float* r1    = (float*)alloc(C2 * 4);

  k_init_a<<<INIT_B + A_B + PMD_B, 256, 0, stream>>>(W1, as1, ad1, msd, Wm1, bm1,
                                                     cnt, slot1, w_att, r1);
  k_scan1<<<(NE_TOT + 1023) / 1024, 256, 0, stream>>>(ei, mip, cnt, slot1, S1, E2);
  k_scan2<<<(NE_TOT + 1023) / 1024, 256, 0, stream>>>(ei, cnt, slot1, E1s, E1d);
  k_bc   <<<32, 256, 0, stream>>>(x, w_att, cnt, S1, E1s, E1d, X1);
  k_d    <<<D_B, 256, 0, stream>>>(X1, W1, cnt, hpart);
  k_e    <<<16, 1024, 0, stream>>>(hpart, b1, W2, cnt, gb);
  k_final<<<1, 512, 0, stream>>>(mip, cnt, slot1, E2, gb, as2, ad2, b2, r1,
                                 Wm2, bm2, Wp1, bp1, Wp2, bp2, Wp3, bp3, out);
}